// Round 10
// baseline (35.926 us; speedup 1.0000x reference)
//
#include <hip/hip_runtime.h>

typedef unsigned long long u64;

#define NPTS 8192
#define DIM  512
#define NK   64
#define TM   64             // rows per tile
#define KP   8              // K-split parts
#define KD   (DIM/KP)       // 64 dims per part
#define NT   (NPTS/TM)      // 128 tiles
#define AP   68             // LDS row pitch (floats): 16B-aligned, bank-spread

// workspace layout (float offsets)
#define WS_DOT  0                         // [KP][NK][NPTS] = 16 MB
#define WS_STAT (KP * NK * NPTS)          // [KP][NPTS] float2
#define WS_G    (WS_STAT + KP * NPTS * 2) // [64][512] gathered centroids
#define WS_SQC  (WS_G + NK * DIM)         // [64]
#define WS_SC   (WS_SQC + NK)             // [64]

// ---------------------------------------------------------------------------
// Prep: gather centroid rows ROW-MAJOR G[k][d] (coalesced copy; gemm's B
// staging then reads it exactly like A), per-centroid stats, zero energy.
// ---------------------------------------------------------------------------
__global__ __launch_bounds__(64) void prep_kernel(
    const float* __restrict__ f, const int* __restrict__ cid,
    float* __restrict__ ws, float* __restrict__ out)
{
    const int k = blockIdx.x;
    const int lane = threadIdx.x;
    if (k == 0 && lane == 0) out[0] = 0.f;
    const float* row = f + (size_t)cid[k] * DIM;
    float4 a = *(const float4*)(row + lane * 8);
    float4 b = *(const float4*)(row + lane * 8 + 4);
    float* g = ws + WS_G + (size_t)k * DIM + lane * 8;
    *(float4*)(g)     = a;
    *(float4*)(g + 4) = b;
    float s = a.x+a.y+a.z+a.w + b.x+b.y+b.z+b.w;
    float q = a.x*a.x+a.y*a.y+a.z*a.z+a.w*a.w
            + b.x*b.x+b.y*b.y+b.z*b.z+b.w*b.w;
    #pragma unroll
    for (int off = 32; off; off >>= 1) {
        s += __shfl_xor(s, off);
        q += __shfl_xor(q, off);
    }
    if (lane == 0) { ws[WS_SQC + k] = q; ws[WS_SC + k] = s; }
}

// ---------------------------------------------------------------------------
// GEMM: 1024 blocks (128 tiles x 8 K-parts) x 256 threads (4 waves/SIMD).
// A and B staged ROW-MAJOR [row][k] (pitch 68 floats = 16B aligned); the
// compute loop reads ALONG K: per 4-dim macro-step, 4 A b128 (16 addrs,
// 8 banks 2-way + 4-way broadcast = free) + 4 B b128 (16-lane broadcast,
// 4 banks = free) feed 64 FMAs -> LDS unique-data ~0.3 B/FMA (R8 was 2,
// 3x over the 85 B/cyc LDS pipe). Rows per thread strided 16 (tr+16r) to
// break the pitch-bank degeneracy. acc[4][4], ~70 VGPR, no min-waves hint.
// ---------------------------------------------------------------------------
__global__ __launch_bounds__(256) void gemm_kernel(
    const float* __restrict__ f, float* __restrict__ ws)
{
    __shared__ float Al[TM * AP];    // 17.4 KB
    __shared__ float Bl[NK * AP];    // 17.4 KB

    const int t     = threadIdx.x;
    const int lane  = t & 63;
    const int w     = t >> 6;
    const int tile  = blockIdx.x >> 3;
    const int kp    = blockIdx.x & 7;
    const int kbase = kp * KD;

    // ---- stage: thread (srow=t>>2, sq=t&3) copies 16 dims of one A row and
    // one centroid row (both coalesced 64B/thread). Row stats ride along.
    const int srow = t >> 2, sq = t & 3;
    const float* fr = f + (size_t)(tile * TM + srow) * DIM + kbase + sq * 16;
    const float* gr = ws + WS_G + (size_t)srow * DIM + kbase + sq * 16;
    float sp = 0.f, qp = 0.f;
    #pragma unroll
    for (int j = 0; j < 4; ++j) {
        float4 a = *(const float4*)(fr + 4 * j);
        sp += (a.x + a.y) + (a.z + a.w);
        qp = fmaf(a.x, a.x, qp); qp = fmaf(a.y, a.y, qp);
        qp = fmaf(a.z, a.z, qp); qp = fmaf(a.w, a.w, qp);
        *(float4*)&Al[srow * AP + sq * 16 + 4 * j] = a;
        *(float4*)&Bl[srow * AP + sq * 16 + 4 * j] = *(const float4*)(gr + 4 * j);
    }
    sp += __shfl_xor(sp, 1); sp += __shfl_xor(sp, 2);
    qp += __shfl_xor(qp, 1); qp += __shfl_xor(qp, 2);
    if (sq == 0)
        ((float2*)(ws + WS_STAT))[(size_t)kp * NPTS + tile * TM + srow] =
            make_float2(sp, qp);
    __syncthreads();          // the only barrier

    // ---- compute: rows {tr+16r}, cols {16w+cg+4c} ----
    const int tr = lane & 15;
    const int cg = lane >> 4;
    float acc[4][4];
    #pragma unroll
    for (int r = 0; r < 4; ++r)
        #pragma unroll
        for (int c = 0; c < 4; ++c) acc[r][c] = 0.f;

    #pragma unroll 4
    for (int g = 0; g < KD / 4; ++g) {
        float4 av[4], bv[4];
        #pragma unroll
        for (int r = 0; r < 4; ++r)
            av[r] = *(const float4*)&Al[(tr + 16 * r) * AP + 4 * g];
        #pragma unroll
        for (int c = 0; c < 4; ++c)
            bv[c] = *(const float4*)&Bl[(16 * w + cg + 4 * c) * AP + 4 * g];
        #pragma unroll
        for (int r = 0; r < 4; ++r)
            #pragma unroll
            for (int c = 0; c < 4; ++c) {
                acc[r][c] = fmaf(av[r].x, bv[c].x, acc[r][c]);
                acc[r][c] = fmaf(av[r].y, bv[c].y, acc[r][c]);
                acc[r][c] = fmaf(av[r].z, bv[c].z, acc[r][c]);
                acc[r][c] = fmaf(av[r].w, bv[c].w, acc[r][c]);
            }
    }

    // ---- store partials [kp][col][point] (16-lane 64B segments) ----
    #pragma unroll
    for (int c = 0; c < 4; ++c) {
        const int col = 16 * w + cg + 4 * c;
        float* dst = ws + WS_DOT + ((size_t)(kp * NK + col)) * NPTS
                   + tile * TM + tr;
        #pragma unroll
        for (int r = 0; r < 4; ++r) dst[16 * r] = acc[r][c];
    }
}

// ---------------------------------------------------------------------------
// Epilogue: 256 blocks x 256 threads (1024 waves). Block owns 32 points;
// thread (p=t&31, grp=t>>5) sums 8 cols x 8 kp partials (coalesced), packed-
// key min; LDS combine across grps; override (last-write-wins) + energy.
// ---------------------------------------------------------------------------
__global__ __launch_bounds__(256) void epi_kernel(
    const float* __restrict__ ws, const int* __restrict__ cid,
    float* __restrict__ out)
{
    __shared__ u64   keys[8][32];
    __shared__ float cqL[NK], csL[NK];
    __shared__ int   cidL[NK];

    const int t   = threadIdx.x;
    const int p   = t & 31;
    const int grp = t >> 5;
    const int gi  = blockIdx.x * 32 + p;

    if (t < NK) { cqL[t] = ws[WS_SQC + t]; csL[t] = ws[WS_SC + t];
                  cidL[t] = cid[t]; }

    float s = 0.f, q = 0.f;
    #pragma unroll
    for (int kp = 0; kp < KP; ++kp) {
        float2 v = ((const float2*)(ws + WS_STAT))[(size_t)kp * NPTS + gi];
        s += v.x; q += v.y;
    }
    __syncthreads();

    u64 key = ~0ull;
    #pragma unroll
    for (int c = 0; c < 8; ++c) {
        const int col = grp * 8 + c;
        float dot = 0.f;
        #pragma unroll
        for (int kp = 0; kp < KP; ++kp)
            dot += ws[WS_DOT + ((size_t)(kp * NK + col)) * NPTS + gi];
        float d2 = q + cqL[col] - 2.f * dot + 2.0e-6f * (s - csL[col])
                 + 5.12e-10f;
        float dist = sqrtf(fmaxf(d2, 0.f));
        u64 kk = (((u64)__float_as_uint(dist)) << 6) | (unsigned)col;
        key = (kk < key) ? kk : key;
    }
    keys[grp][p] = key;
    __syncthreads();

    if (t < 32) {
        u64 kmin = keys[0][t];
        #pragma unroll
        for (int j = 1; j < 8; ++j) {
            u64 o = keys[j][t];
            kmin = (o < kmin) ? o : kmin;
        }
        const int gp = blockIdx.x * 32 + t;
        float y = (float)(unsigned)(kmin & 63ull);
        for (int k = 0; k < NK; ++k)
            if (cidL[k] == gp) y = (float)k;           // last write wins
        out[1 + gp] = y;
        float e = __uint_as_float((unsigned)(kmin >> 6));
        #pragma unroll
        for (int off = 16; off; off >>= 1) e += __shfl_xor(e, off);
        if (t == 0) atomicAdd(out, -e);
    }
}

extern "C" void kernel_launch(void* const* d_in, const int* in_sizes, int n_in,
                              void* d_out, int out_size, void* d_ws, size_t ws_size,
                              hipStream_t stream) {
    const float* f   = (const float*)d_in[0];
    const int*   cid = (const int*)d_in[1];
    float*       out = (float*)d_out;
    float*       ws  = (float*)d_ws;     // ~17.4 MB used

    prep_kernel<<<NK, 64, 0, stream>>>(f, cid, ws, out);
    gemm_kernel<<<NT * KP, 256, 0, stream>>>(f, ws);
    epi_kernel<<<NPTS / 32, 256, 0, stream>>>(ws, cid, out);
}